// Round 16
// baseline (337.540 us; speedup 1.0000x reference)
//
#include <hip/hip_runtime.h>

typedef unsigned short u16;
typedef unsigned char u8;
typedef __attribute__((ext_vector_type(8))) short short8;
typedef __attribute__((ext_vector_type(2))) float f32x2;
typedef __attribute__((ext_vector_type(4))) float f32x4;
typedef __attribute__((ext_vector_type(4))) unsigned short us4;
typedef __attribute__((ext_vector_type(8))) unsigned short us8;
typedef __attribute__((ext_vector_type(4))) unsigned int u32x4;

#define N_NODES 50000
#define N_EDGES 800000
#define DIM 128
#define NINV (1.0f / 50000.0f)
#define NPART 8
#define PART_SZ 6250  /* 50000/8 */
#define SROW 136      /* LDS row stride (u16) */
#define CHUNK 49      /* scan: 1024*49 = 50176 >= 50000 */

__device__ __forceinline__ float bf2f(u16 u) {
    union { unsigned int i; float f; } v; v.i = ((unsigned int)u) << 16; return v.f;
}
__device__ __forceinline__ u16 f2bf(float f) {
    union { float f; unsigned int i; } v; v.f = f;
    return (u16)((v.i + 0x7FFFu + ((v.i >> 16) & 1u)) >> 16);
}

// ---------------- single-kernel exclusive scan (deg -> row_ptr, cursor) ----------------
// One block, 1024 threads; thread t owns deg[t*49 .. t*49+48].
__global__ __launch_bounds__(1024) void k_scan(
        const int* __restrict__ deg, int* __restrict__ row_ptr, int* __restrict__ cursor) {
    __shared__ int sd[1024];
    int t = threadIdx.x;
    int base = t * CHUNK;
    int loc[CHUNK];
    int s = 0;
    #pragma unroll
    for (int k = 0; k < CHUNK; ++k) {
        int i = base + k;
        int v = (i < N_NODES) ? deg[i] : 0;
        loc[k] = s;          // exclusive within chunk
        s += v;
    }
    sd[t] = s; __syncthreads();
    // Hillis-Steele inclusive scan of 1024 partials
    for (int o = 1; o < 1024; o <<= 1) {
        int x = sd[t] + ((t >= o) ? sd[t - o] : 0);
        __syncthreads(); sd[t] = x; __syncthreads();
    }
    int pre = (t > 0) ? sd[t - 1] : 0;   // exclusive prefix for this chunk
    #pragma unroll
    for (int k = 0; k < CHUNK; ++k) {
        int i = base + k;
        if (i < N_NODES) {
            int rp = pre + loc[k];
            row_ptr[i] = rp;
            cursor[i] = rp;
        }
    }
    if (t == 1023) row_ptr[N_NODES] = N_EDGES;
}

// XCD-partitioned fill (see R12): part = blockIdx&7, chunk = blockIdx>>3.
__global__ __launch_bounds__(256) void k_fill(
        const int* __restrict__ src, const int* __restrict__ dst,
        int* __restrict__ cursor, u16* __restrict__ col_src) {
    int part = blockIdx.x & 7;
    int e = (blockIdx.x >> 3) * 256 + threadIdx.x;
    if (e < N_EDGES) {
        int d = dst[e];
        if ((unsigned)(d - part * PART_SZ) < (unsigned)PART_SZ) {
            int pos = atomicAdd(&cursor[d], 1);
            col_src[pos] = (u16)src[e];
        }
    }
}

// ---------------- prep: pack B1/B2, split x, XCD-partitioned degree histogram ----------------
// blocks 0..15: pack B1; 16..31: pack B2; 32..32+splitB-1: split x;
// rest: partitioned hist (part = idx&7, chunk = idx>>3).
__global__ __launch_bounds__(256) void k_prep(
        const float* __restrict__ W1l, const float* __restrict__ W1r, u16* __restrict__ Bp1,
        const float* __restrict__ W2l, const float* __restrict__ W2r, u16* __restrict__ Bp2,
        const float* __restrict__ x, u16* __restrict__ xh, u8* __restrict__ xf8,
        const int* __restrict__ edst, int* __restrict__ deg, int splitB) {
    int b = blockIdx.x;
    if (b < 32) {
        const float* Wl = (b < 16) ? W1l : W2l;
        const float* Wr = (b < 16) ? W1r : W2r;
        u16* Bp = (b < 16) ? Bp1 : Bp2;
        int idx = (b & 15) * 256 + threadIdx.x;      // 0..4095
        int lane = idx & 63;
        int kc = (idx >> 6) & 7;
        int nt = idx >> 9;
        int q = lane >> 4, nn = lane & 15;
        int col = nt * 16 + nn;
        #pragma unroll
        for (int j = 0; j < 8; ++j) {
            int k = kc * 32 + q * 8 + j;
            float v = (k < 128) ? Wl[k * 128 + col] : Wr[(k - 128) * 128 + col];
            Bp[(long)idx * 8 + j] = f2bf(v);
        }
    } else if (b < 32 + splitB) {
        long i4 = ((long)(b - 32) * 256 + threadIdx.x) * 4;
        f32x4 v = *(const f32x4*)(x + i4);
        us4 h;
        #pragma unroll
        for (int j = 0; j < 4; ++j) h[j] = f2bf(v[j]);
        *(us4*)(xh + i4) = h;
        int p = __builtin_amdgcn_cvt_pk_fp8_f32(v[0], v[1], 0, false);
        p = __builtin_amdgcn_cvt_pk_fp8_f32(v[2], v[3], p, true);
        *(int*)(xf8 + i4) = p;
    } else {
        int hb = b - 32 - splitB;
        int part = hb & 7;
        int e = (hb >> 3) * 256 + threadIdx.x;
        if (e < N_EDGES) {
            int d = edst[e];
            if ((unsigned)(d - part * PART_SZ) < (unsigned)PART_SZ)
                atomicAdd(&deg[d], 1);
        }
    }
}

// decode 16 fp8 + (optional BN+relu) + accumulate
template<int BN>
__device__ __forceinline__ void acc_row16(u32x4 w,
        float sum[16], const float av[16], const float ov[16]) {
    float t[16];
    f32x2 p;
    #pragma unroll
    for (int h = 0; h < 4; ++h) {
        p = __builtin_amdgcn_cvt_pk_f32_fp8((int)w[h], false); t[h*4+0] = p[0]; t[h*4+1] = p[1];
        p = __builtin_amdgcn_cvt_pk_f32_fp8((int)w[h], true);  t[h*4+2] = p[0]; t[h*4+3] = p[1];
    }
    #pragma unroll
    for (int k = 0; k < 16; ++k) {
        float v = t[k];
        if (BN) { v = v * av[k] + ov[k]; v = v > 0.f ? v : 0.f; }
        sum[k] += v;
    }
}

// ---------------- fused AGG + GEMM + BN stats ----------------
template<int BN, int W8>
__global__ __launch_bounds__(256) void k_ag(
        const u8* __restrict__ fq, const u16* __restrict__ fh,
        const int* __restrict__ row_ptr, const u16* __restrict__ col_src,
        const u16* __restrict__ Bph, const float* __restrict__ bias,
        const float* __restrict__ statsPrev, const float* __restrict__ gP,
        const float* __restrict__ btP,
        u16* __restrict__ h16, u8* __restrict__ h8, float* __restrict__ stats) {
    __shared__ u16 sA[16 * SROW];
    __shared__ float acS[256];
    int tid = threadIdx.x;
    long nodebase = (long)blockIdx.x * 16;       // 3125*16 == 50000 exact

    if (BN) {
        if (tid < 128) {
            float s = 0.f, qq = 0.f;
            #pragma unroll
            for (int b = 0; b < 8; ++b) {
                s  += statsPrev[b * 512 + tid];
                qq += statsPrev[b * 512 + 256 + tid];
            }
            float mu = s * NINV;
            float var = qq * NINV - mu * mu;
            float a = gP[tid] * rsqrtf(var + 1e-5f);
            acS[tid] = a;
            acS[128 + tid] = btP[tid] - mu * a;
        }
        __syncthreads();
    }

    // ---- phase 1: gather-mean (fp8, 16B/lane, even/odd edge split) ----
    {
        int grp = tid >> 4;          // node 0..15
        int g   = tid & 15;
        int sub = g >> 3;            // 0: even edges, 1: odd edges
        int gl  = g & 7;
        int d16 = gl * 16;           // dim base
        int node = (int)nodebase + grp;
        int s = row_ptr[node], e = row_ptr[node + 1];
        float av[16], ov[16];
        if (BN) {
            #pragma unroll
            for (int k = 0; k < 16; ++k) { av[k] = acS[d16 + k]; ov[k] = acS[128 + d16 + k]; }
        }
        float sum[16];
        #pragma unroll
        for (int k = 0; k < 16; ++k) sum[k] = 0.f;
        int j = s + sub;
        for (; j + 6 < e; j += 8) {
            int i0 = col_src[j], i1 = col_src[j + 2], i2 = col_src[j + 4], i3 = col_src[j + 6];
            u32x4 w0 = *(const u32x4*)(fq + (long)i0 * DIM + d16);
            u32x4 w1 = *(const u32x4*)(fq + (long)i1 * DIM + d16);
            u32x4 w2 = *(const u32x4*)(fq + (long)i2 * DIM + d16);
            u32x4 w3 = *(const u32x4*)(fq + (long)i3 * DIM + d16);
            acc_row16<BN>(w0, sum, av, ov);
            acc_row16<BN>(w1, sum, av, ov);
            acc_row16<BN>(w2, sum, av, ov);
            acc_row16<BN>(w3, sum, av, ov);
        }
        for (; j < e; j += 2) {
            int i0 = col_src[j];
            u32x4 w0 = *(const u32x4*)(fq + (long)i0 * DIM + d16);
            acc_row16<BN>(w0, sum, av, ov);
        }
        // combine even/odd halves
        #pragma unroll
        for (int k = 0; k < 16; ++k) sum[k] += __shfl_xor(sum[k], 8);
        if (sub == 0) {
            float dn = (e > s) ? 1.f / (float)(e - s) : 1.f;
            us8 r0, r1;
            #pragma unroll
            for (int k = 0; k < 8; ++k) {
                r0[k] = f2bf(sum[k] * dn);
                r1[k] = f2bf(sum[8 + k] * dn);
            }
            *(us8*)(sA + grp * SROW + d16) = r0;
            *(us8*)(sA + grp * SROW + d16 + 8) = r1;
        }
    }
    __syncthreads();

    // ---- phase 2: MFMA ----
    int cg = tid >> 6, lane = tid & 63;
    int q = lane >> 4, nn = lane & 15;
    long rc = nodebase + nn;

    short8 ah[8];
    #pragma unroll
    for (int kc = 0; kc < 4; ++kc)
        ah[kc] = *(const short8*)(sA + nn * SROW + kc * 32 + q * 8);
    #pragma unroll
    for (int kc = 0; kc < 4; ++kc) {
        int ko = kc * 32 + q * 8;
        us8 rv = *(const us8*)(fh + rc * DIM + ko);
        short8 t;
        if (BN) {
            #pragma unroll
            for (int j = 0; j < 8; ++j) {
                float v = bf2f(rv[j]) * acS[ko + j] + acS[128 + ko + j];
                t[j] = (short)f2bf(v > 0.f ? v : 0.f);
            }
        } else {
            #pragma unroll
            for (int j = 0; j < 8; ++j) t[j] = (short)rv[j];
        }
        ah[4 + kc] = t;
    }

    f32x4 acc[2];
    acc[0] = (f32x4){0.f, 0.f, 0.f, 0.f};
    acc[1] = (f32x4){0.f, 0.f, 0.f, 0.f};

    #pragma unroll
    for (int kc = 0; kc < 8; ++kc) {
        #pragma unroll
        for (int nt = 0; nt < 2; ++nt) {
            int ntg = cg * 2 + nt;
            short8 bh = *(const short8*)(Bph + (((ntg * 8 + kc) * 64 + lane) << 3));
            acc[nt] = __builtin_amdgcn_mfma_f32_16x16x32_bf16(ah[kc], bh, acc[nt], 0, 0, 0);
        }
    }

    int bank = blockIdx.x & 7;
    #pragma unroll
    for (int nt = 0; nt < 2; ++nt) {
        int col = cg * 32 + nt * 16 + nn;
        float bv = bias[col];
        float ps = 0.f, pq = 0.f;
        #pragma unroll
        for (int r = 0; r < 4; ++r) {
            float v = acc[nt][r] + bv;
            long idx = (nodebase + q * 4 + r) * DIM + col;
            h16[idx] = f2bf(v);
            if (W8) {
                int pb = __builtin_amdgcn_cvt_pk_fp8_f32(v, v, 0, false);
                h8[idx] = (u8)(pb & 0xff);
            }
            ps += v; pq += v * v;
        }
        ps += __shfl_xor(ps, 16);
        ps += __shfl_xor(ps, 32);
        pq += __shfl_xor(pq, 16);
        pq += __shfl_xor(pq, 32);
        if (q == 0) {
            atomicAdd(&stats[bank * 512 + col], ps);
            atomicAdd(&stats[bank * 512 + 256 + col], pq);
        }
    }
}

// out = relu(bn(h)+x); coeffs computed in-block from banked stats
__global__ __launch_bounds__(256) void k_bn_add_relu(
        const u16* __restrict__ h, const float* __restrict__ stats,
        const float* __restrict__ g, const float* __restrict__ bt,
        const float* __restrict__ x, float* __restrict__ outv) {
    __shared__ float acS[256];
    int tid = threadIdx.x;
    if (tid < 128) {
        float s = 0.f, qq = 0.f;
        #pragma unroll
        for (int b = 0; b < 8; ++b) {
            s  += stats[b * 512 + tid];
            qq += stats[b * 512 + 256 + tid];
        }
        float mu = s * NINV;
        float var = qq * NINV - mu * mu;
        float a = g[tid] * rsqrtf(var + 1e-5f);
        acS[tid] = a;
        acS[128 + tid] = bt[tid] - mu * a;
    }
    __syncthreads();
    long i8 = ((long)blockIdx.x * 256 + tid) * 8;
    int c = (int)(i8 & 127);
    us8 hv = *(const us8*)(h + i8);
    f32x4 x0 = *(const f32x4*)(x + i8);
    f32x4 x1 = *(const f32x4*)(x + i8 + 4);
    f32x4 r0, r1;
    #pragma unroll
    for (int j = 0; j < 4; ++j) {
        float v = bf2f(hv[j]) * acS[c + j] + acS[128 + c + j] + x0[j];
        r0[j] = v > 0.f ? v : 0.f;
        float w = bf2f(hv[4 + j]) * acS[c + 4 + j] + acS[128 + c + 4 + j] + x1[j];
        r1[j] = w > 0.f ? w : 0.f;
    }
    *(f32x4*)(outv + i8) = r0;
    *(f32x4*)(outv + i8 + 4) = r1;
}

extern "C" void kernel_launch(void* const* d_in, const int* in_sizes, int n_in,
                              void* d_out, int out_size, void* d_ws, size_t ws_size,
                              hipStream_t stream) {
    (void)in_sizes; (void)n_in; (void)out_size; (void)ws_size;
    const float* x   = (const float*)d_in[0];
    const int*   ei  = (const int*)d_in[1];
    const float* W1l = (const float*)d_in[2];
    const float* b1  = (const float*)d_in[3];
    const float* W1r = (const float*)d_in[4];
    const float* g1  = (const float*)d_in[5];
    const float* bt1 = (const float*)d_in[6];
    const float* W2l = (const float*)d_in[7];
    const float* b2  = (const float*)d_in[8];
    const float* W2r = (const float*)d_in[9];
    const float* g2  = (const float*)d_in[10];
    const float* bt2 = (const float*)d_in[11];
    float* out = (float*)d_out;

    const int* esrc = ei;
    const int* edst = ei + N_EDGES;

    char* ws = (char*)d_ws;
    size_t off = 0;
    auto alloc = [&](size_t bytes) { size_t p = off; off = (off + bytes + 255) & ~(size_t)255; return p; };
    int*   deg     = (int*)  (ws + alloc(N_NODES * 4));
    float* stats1  = (float*)(ws + alloc(4096 * 4));   // 8 banks x 512 (sum@+col, sumsq@+256+col)
    float* stats2  = (float*)(ws + alloc(4096 * 4));
    size_t zero_bytes = off;                       // everything above must be zeroed
    int*   cursor  = (int*)  (ws + alloc(N_NODES * 4));
    int*   row_ptr = (int*)  (ws + alloc((N_NODES + 1) * 4));
    u16*   col_src = (u16*)  (ws + alloc((size_t)N_EDGES * 2));
    u16*   xh      = (u16*)  (ws + alloc((size_t)N_NODES * DIM * 2));
    u8*    xf8     = (u8*)   (ws + alloc((size_t)N_NODES * DIM));
    u16*   hb1     = (u16*)  (ws + alloc((size_t)N_NODES * DIM * 2));  // raw h1 bf16
    u8*    h1f8    = (u8*)   (ws + alloc((size_t)N_NODES * DIM));     // raw h1 fp8
    u16*   hb2     = (u16*)  (ws + alloc((size_t)N_NODES * DIM * 2));  // raw h2 bf16
    u16*   Bp1h    = (u16*)  (ws + alloc(256 * 128 * 2));
    u16*   Bp2h    = (u16*)  (ws + alloc(256 * 128 * 2));

    hipMemsetAsync(ws, 0, zero_bytes, stream);

    const int EB = (N_EDGES + 255) / 256;            // 3125
    const int FILLB = EB * NPART;                    // 25000
    const int AGB = N_NODES / 16;                    // 3125 exact
    const int EWB4 = (int)(((long)N_NODES * DIM) / 1024);  // 6250 exact
    const int EWB8 = (int)(((long)N_NODES * DIM) / 2048);  // 3125 exact
    const int PREPB = 32 + EWB4 + FILLB;             // pack + split + partitioned hist

    // prep: pack both B + split x (bf16 + fp8) + XCD-partitioned degree histogram
    k_prep<<<PREPB, 256, 0, stream>>>(W1l, W1r, Bp1h, W2l, W2r, Bp2h, x, xh, xf8,
                                      edst, deg, EWB4);

    // single-kernel exclusive scan -> row_ptr, cursor
    k_scan<<<1, 1024, 0, stream>>>(deg, row_ptr, cursor);

    // CSR fill
    k_fill<<<FILLB, 256, 0, stream>>>(esrc, edst, cursor, col_src);

    // stage 1: fused agg+gemm on x (fp8 gather, bf16 root); writes h1 bf16 + fp8
    k_ag<0, 1><<<AGB, 256, 0, stream>>>(xf8, xh, row_ptr, col_src, Bp1h, b1,
                                        stats1, g1, bt1, hb1, h1f8, stats1);

    // stage 2: fused agg+gemm on h1 with BN+relu at operand load (coeffs from stats1)
    k_ag<1, 0><<<AGB, 256, 0, stream>>>(h1f8, hb1, row_ptr, col_src, Bp2h, b2,
                                        stats1, g1, bt1, hb2, h1f8, stats2);

    // epilogue: out = relu(bn(h2) + x), coeffs from stats2
    k_bn_add_relu<<<EWB8, 256, 0, stream>>>(hb2, stats2, g2, bt2, x, out);
}

// Round 17
// 262.090 us; speedup vs baseline: 1.2879x; 1.2879x over previous
//
#include <hip/hip_runtime.h>

typedef unsigned short u16;
typedef unsigned char u8;
typedef __attribute__((ext_vector_type(8))) short short8;
typedef __attribute__((ext_vector_type(2))) float f32x2;
typedef __attribute__((ext_vector_type(4))) float f32x4;
typedef __attribute__((ext_vector_type(4))) unsigned short us4;
typedef __attribute__((ext_vector_type(8))) unsigned short us8;
typedef __attribute__((ext_vector_type(4))) unsigned int u32x4;

#define N_NODES 50000
#define N_EDGES 800000
#define DIM 128
#define SCAN_B 196   /* ceil(50000/256) */
#define NINV (1.0f / 50000.0f)
#define NPART 8
#define PART_SZ 6250  /* 50000/8 */
#define SROW 136      /* LDS row stride (u16) */

__device__ __forceinline__ float bf2f(u16 u) {
    union { unsigned int i; float f; } v; v.i = ((unsigned int)u) << 16; return v.f;
}
__device__ __forceinline__ u16 f2bf(float f) {
    union { float f; unsigned int i; } v; v.f = f;
    return (u16)((v.i + 0x7FFFu + ((v.i >> 16) & 1u)) >> 16);
}

// ---------------- CSR scans (3-kernel, parallel — proven structure) ----------------

__global__ void k_scan1(const int* __restrict__ deg, int* __restrict__ bsum) {
    __shared__ int sd[256];
    int t = threadIdx.x; int i = blockIdx.x * 256 + t;
    sd[t] = (i < N_NODES) ? deg[i] : 0;
    __syncthreads();
    for (int o = 128; o > 0; o >>= 1) { if (t < o) sd[t] += sd[t + o]; __syncthreads(); }
    if (t == 0) bsum[blockIdx.x] = sd[0];
}

__global__ void k_scan2(const int* __restrict__ bsum, int* __restrict__ bpre) {
    __shared__ int sd[256];
    int t = threadIdx.x;
    int v = (t < SCAN_B) ? bsum[t] : 0;
    sd[t] = v; __syncthreads();
    for (int o = 1; o < 256; o <<= 1) {
        int x = sd[t] + ((t >= o) ? sd[t - o] : 0);
        __syncthreads(); sd[t] = x; __syncthreads();
    }
    if (t < SCAN_B) bpre[t] = sd[t] - v;   // exclusive
}

__global__ void k_scan3(const int* __restrict__ deg, const int* __restrict__ bpre,
                        int* __restrict__ row_ptr, int* __restrict__ cursor) {
    __shared__ int sd[256];
    int t = threadIdx.x; int i = blockIdx.x * 256 + t;
    int v = (i < N_NODES) ? deg[i] : 0;
    sd[t] = v; __syncthreads();
    for (int o = 1; o < 256; o <<= 1) {
        int x = sd[t] + ((t >= o) ? sd[t - o] : 0);
        __syncthreads(); sd[t] = x; __syncthreads();
    }
    if (i <= N_NODES) {
        int rp = bpre[blockIdx.x] + sd[t] - v;   // i==N gets E
        row_ptr[i] = rp;
        if (i < N_NODES) cursor[i] = rp;
    }
}

// XCD-partitioned fill (see R12): part = blockIdx&7, chunk = blockIdx>>3.
__global__ __launch_bounds__(256) void k_fill(
        const int* __restrict__ src, const int* __restrict__ dst,
        int* __restrict__ cursor, u16* __restrict__ col_src) {
    int part = blockIdx.x & 7;
    int e = (blockIdx.x >> 3) * 256 + threadIdx.x;
    if (e < N_EDGES) {
        int d = dst[e];
        if ((unsigned)(d - part * PART_SZ) < (unsigned)PART_SZ) {
            int pos = atomicAdd(&cursor[d], 1);
            col_src[pos] = (u16)src[e];
        }
    }
}

// ---------------- prep: pack B1/B2, split x, XCD-partitioned degree histogram ----------------
// blocks 0..15: pack B1; 16..31: pack B2; 32..32+splitB-1: split x;
// rest: partitioned hist (part = idx&7, chunk = idx>>3).
__global__ __launch_bounds__(256) void k_prep(
        const float* __restrict__ W1l, const float* __restrict__ W1r, u16* __restrict__ Bp1,
        const float* __restrict__ W2l, const float* __restrict__ W2r, u16* __restrict__ Bp2,
        const float* __restrict__ x, u16* __restrict__ xh, u8* __restrict__ xf8,
        const int* __restrict__ edst, int* __restrict__ deg, int splitB) {
    int b = blockIdx.x;
    if (b < 32) {
        const float* Wl = (b < 16) ? W1l : W2l;
        const float* Wr = (b < 16) ? W1r : W2r;
        u16* Bp = (b < 16) ? Bp1 : Bp2;
        int idx = (b & 15) * 256 + threadIdx.x;      // 0..4095
        int lane = idx & 63;
        int kc = (idx >> 6) & 7;
        int nt = idx >> 9;
        int q = lane >> 4, nn = lane & 15;
        int col = nt * 16 + nn;
        #pragma unroll
        for (int j = 0; j < 8; ++j) {
            int k = kc * 32 + q * 8 + j;
            float v = (k < 128) ? Wl[k * 128 + col] : Wr[(k - 128) * 128 + col];
            Bp[(long)idx * 8 + j] = f2bf(v);
        }
    } else if (b < 32 + splitB) {
        long i4 = ((long)(b - 32) * 256 + threadIdx.x) * 4;
        f32x4 v = *(const f32x4*)(x + i4);
        us4 h;
        #pragma unroll
        for (int j = 0; j < 4; ++j) h[j] = f2bf(v[j]);
        *(us4*)(xh + i4) = h;
        int p = __builtin_amdgcn_cvt_pk_fp8_f32(v[0], v[1], 0, false);
        p = __builtin_amdgcn_cvt_pk_fp8_f32(v[2], v[3], p, true);
        *(int*)(xf8 + i4) = p;
    } else {
        int hb = b - 32 - splitB;
        int part = hb & 7;
        int e = (hb >> 3) * 256 + threadIdx.x;
        if (e < N_EDGES) {
            int d = edst[e];
            if ((unsigned)(d - part * PART_SZ) < (unsigned)PART_SZ)
                atomicAdd(&deg[d], 1);
        }
    }
}

// decode 16 fp8 + (optional BN+relu) + accumulate
template<int BN>
__device__ __forceinline__ void acc_row16(u32x4 w,
        float sum[16], const float av[16], const float ov[16]) {
    float t[16];
    f32x2 p;
    #pragma unroll
    for (int h = 0; h < 4; ++h) {
        p = __builtin_amdgcn_cvt_pk_f32_fp8((int)w[h], false); t[h*4+0] = p[0]; t[h*4+1] = p[1];
        p = __builtin_amdgcn_cvt_pk_f32_fp8((int)w[h], true);  t[h*4+2] = p[0]; t[h*4+3] = p[1];
    }
    #pragma unroll
    for (int k = 0; k < 16; ++k) {
        float v = t[k];
        if (BN) { v = v * av[k] + ov[k]; v = v > 0.f ? v : 0.f; }
        sum[k] += v;
    }
}

// ---------------- fused AGG + GEMM + BN stats ----------------
template<int BN, int W8>
__global__ __launch_bounds__(256) void k_ag(
        const u8* __restrict__ fq, const u16* __restrict__ fh,
        const int* __restrict__ row_ptr, const u16* __restrict__ col_src,
        const u16* __restrict__ Bph, const float* __restrict__ bias,
        const float* __restrict__ statsPrev, const float* __restrict__ gP,
        const float* __restrict__ btP,
        u16* __restrict__ h16, u8* __restrict__ h8, float* __restrict__ stats) {
    __shared__ u16 sA[16 * SROW];
    __shared__ float acS[256];
    int tid = threadIdx.x;
    long nodebase = (long)blockIdx.x * 16;       // 3125*16 == 50000 exact

    if (BN) {
        if (tid < 128) {
            float s = 0.f, qq = 0.f;
            #pragma unroll
            for (int b = 0; b < 8; ++b) {
                s  += statsPrev[b * 512 + tid];
                qq += statsPrev[b * 512 + 256 + tid];
            }
            float mu = s * NINV;
            float var = qq * NINV - mu * mu;
            float a = gP[tid] * rsqrtf(var + 1e-5f);
            acS[tid] = a;
            acS[128 + tid] = btP[tid] - mu * a;
        }
        __syncthreads();
    }

    // ---- phase 1: gather-mean (fp8, 16B/lane, even/odd edge split) ----
    {
        int grp = tid >> 4;          // node 0..15
        int g   = tid & 15;
        int sub = g >> 3;            // 0: even edges, 1: odd edges
        int gl  = g & 7;
        int d16 = gl * 16;           // dim base
        int node = (int)nodebase + grp;
        int s = row_ptr[node], e = row_ptr[node + 1];
        float av[16], ov[16];
        if (BN) {
            #pragma unroll
            for (int k = 0; k < 16; ++k) { av[k] = acS[d16 + k]; ov[k] = acS[128 + d16 + k]; }
        }
        float sum[16];
        #pragma unroll
        for (int k = 0; k < 16; ++k) sum[k] = 0.f;
        int j = s + sub;
        for (; j + 6 < e; j += 8) {
            int i0 = col_src[j], i1 = col_src[j + 2], i2 = col_src[j + 4], i3 = col_src[j + 6];
            u32x4 w0 = *(const u32x4*)(fq + (long)i0 * DIM + d16);
            u32x4 w1 = *(const u32x4*)(fq + (long)i1 * DIM + d16);
            u32x4 w2 = *(const u32x4*)(fq + (long)i2 * DIM + d16);
            u32x4 w3 = *(const u32x4*)(fq + (long)i3 * DIM + d16);
            acc_row16<BN>(w0, sum, av, ov);
            acc_row16<BN>(w1, sum, av, ov);
            acc_row16<BN>(w2, sum, av, ov);
            acc_row16<BN>(w3, sum, av, ov);
        }
        for (; j < e; j += 2) {
            int i0 = col_src[j];
            u32x4 w0 = *(const u32x4*)(fq + (long)i0 * DIM + d16);
            acc_row16<BN>(w0, sum, av, ov);
        }
        // combine even/odd halves
        #pragma unroll
        for (int k = 0; k < 16; ++k) sum[k] += __shfl_xor(sum[k], 8);
        if (sub == 0) {
            float dn = (e > s) ? 1.f / (float)(e - s) : 1.f;
            us8 r0, r1;
            #pragma unroll
            for (int k = 0; k < 8; ++k) {
                r0[k] = f2bf(sum[k] * dn);
                r1[k] = f2bf(sum[8 + k] * dn);
            }
            *(us8*)(sA + grp * SROW + d16) = r0;
            *(us8*)(sA + grp * SROW + d16 + 8) = r1;
        }
    }
    __syncthreads();

    // ---- phase 2: MFMA ----
    int cg = tid >> 6, lane = tid & 63;
    int q = lane >> 4, nn = lane & 15;
    long rc = nodebase + nn;

    short8 ah[8];
    #pragma unroll
    for (int kc = 0; kc < 4; ++kc)
        ah[kc] = *(const short8*)(sA + nn * SROW + kc * 32 + q * 8);
    #pragma unroll
    for (int kc = 0; kc < 4; ++kc) {
        int ko = kc * 32 + q * 8;
        us8 rv = *(const us8*)(fh + rc * DIM + ko);
        short8 t;
        if (BN) {
            #pragma unroll
            for (int j = 0; j < 8; ++j) {
                float v = bf2f(rv[j]) * acS[ko + j] + acS[128 + ko + j];
                t[j] = (short)f2bf(v > 0.f ? v : 0.f);
            }
        } else {
            #pragma unroll
            for (int j = 0; j < 8; ++j) t[j] = (short)rv[j];
        }
        ah[4 + kc] = t;
    }

    f32x4 acc[2];
    acc[0] = (f32x4){0.f, 0.f, 0.f, 0.f};
    acc[1] = (f32x4){0.f, 0.f, 0.f, 0.f};

    #pragma unroll
    for (int kc = 0; kc < 8; ++kc) {
        #pragma unroll
        for (int nt = 0; nt < 2; ++nt) {
            int ntg = cg * 2 + nt;
            short8 bh = *(const short8*)(Bph + (((ntg * 8 + kc) * 64 + lane) << 3));
            acc[nt] = __builtin_amdgcn_mfma_f32_16x16x32_bf16(ah[kc], bh, acc[nt], 0, 0, 0);
        }
    }

    int bank = blockIdx.x & 7;
    #pragma unroll
    for (int nt = 0; nt < 2; ++nt) {
        int col = cg * 32 + nt * 16 + nn;
        float bv = bias[col];
        float ps = 0.f, pq = 0.f;
        #pragma unroll
        for (int r = 0; r < 4; ++r) {
            float v = acc[nt][r] + bv;
            long idx = (nodebase + q * 4 + r) * DIM + col;
            h16[idx] = f2bf(v);
            if (W8) {
                int pb = __builtin_amdgcn_cvt_pk_fp8_f32(v, v, 0, false);
                h8[idx] = (u8)(pb & 0xff);
            }
            ps += v; pq += v * v;
        }
        ps += __shfl_xor(ps, 16);
        ps += __shfl_xor(ps, 32);
        pq += __shfl_xor(pq, 16);
        pq += __shfl_xor(pq, 32);
        if (q == 0) {
            atomicAdd(&stats[bank * 512 + col], ps);
            atomicAdd(&stats[bank * 512 + 256 + col], pq);
        }
    }
}

// out = relu(bn(h)+x); coeffs computed in-block from banked stats
__global__ __launch_bounds__(256) void k_bn_add_relu(
        const u16* __restrict__ h, const float* __restrict__ stats,
        const float* __restrict__ g, const float* __restrict__ bt,
        const float* __restrict__ x, float* __restrict__ outv) {
    __shared__ float acS[256];
    int tid = threadIdx.x;
    if (tid < 128) {
        float s = 0.f, qq = 0.f;
        #pragma unroll
        for (int b = 0; b < 8; ++b) {
            s  += stats[b * 512 + tid];
            qq += stats[b * 512 + 256 + tid];
        }
        float mu = s * NINV;
        float var = qq * NINV - mu * mu;
        float a = g[tid] * rsqrtf(var + 1e-5f);
        acS[tid] = a;
        acS[128 + tid] = bt[tid] - mu * a;
    }
    __syncthreads();
    long i8 = ((long)blockIdx.x * 256 + tid) * 8;
    int c = (int)(i8 & 127);
    us8 hv = *(const us8*)(h + i8);
    f32x4 x0 = *(const f32x4*)(x + i8);
    f32x4 x1 = *(const f32x4*)(x + i8 + 4);
    f32x4 r0, r1;
    #pragma unroll
    for (int j = 0; j < 4; ++j) {
        float v = bf2f(hv[j]) * acS[c + j] + acS[128 + c + j] + x0[j];
        r0[j] = v > 0.f ? v : 0.f;
        float w = bf2f(hv[4 + j]) * acS[c + 4 + j] + acS[128 + c + 4 + j] + x1[j];
        r1[j] = w > 0.f ? w : 0.f;
    }
    *(f32x4*)(outv + i8) = r0;
    *(f32x4*)(outv + i8 + 4) = r1;
}

extern "C" void kernel_launch(void* const* d_in, const int* in_sizes, int n_in,
                              void* d_out, int out_size, void* d_ws, size_t ws_size,
                              hipStream_t stream) {
    (void)in_sizes; (void)n_in; (void)out_size; (void)ws_size;
    const float* x   = (const float*)d_in[0];
    const int*   ei  = (const int*)d_in[1];
    const float* W1l = (const float*)d_in[2];
    const float* b1  = (const float*)d_in[3];
    const float* W1r = (const float*)d_in[4];
    const float* g1  = (const float*)d_in[5];
    const float* bt1 = (const float*)d_in[6];
    const float* W2l = (const float*)d_in[7];
    const float* b2  = (const float*)d_in[8];
    const float* W2r = (const float*)d_in[9];
    const float* g2  = (const float*)d_in[10];
    const float* bt2 = (const float*)d_in[11];
    float* out = (float*)d_out;

    const int* esrc = ei;
    const int* edst = ei + N_EDGES;

    char* ws = (char*)d_ws;
    size_t off = 0;
    auto alloc = [&](size_t bytes) { size_t p = off; off = (off + bytes + 255) & ~(size_t)255; return p; };
    int*   deg     = (int*)  (ws + alloc(N_NODES * 4));
    float* stats1  = (float*)(ws + alloc(4096 * 4));   // 8 banks x 512 (sum@+col, sumsq@+256+col)
    float* stats2  = (float*)(ws + alloc(4096 * 4));
    size_t zero_bytes = off;                       // everything above must be zeroed
    int*   cursor  = (int*)  (ws + alloc(N_NODES * 4));
    int*   row_ptr = (int*)  (ws + alloc((N_NODES + 1) * 4));
    int*   bsum    = (int*)  (ws + alloc(256 * 4));
    int*   bpre    = (int*)  (ws + alloc(256 * 4));
    u16*   col_src = (u16*)  (ws + alloc((size_t)N_EDGES * 2));
    u16*   xh      = (u16*)  (ws + alloc((size_t)N_NODES * DIM * 2));
    u8*    xf8     = (u8*)   (ws + alloc((size_t)N_NODES * DIM));
    u16*   hb1     = (u16*)  (ws + alloc((size_t)N_NODES * DIM * 2));  // raw h1 bf16
    u8*    h1f8    = (u8*)   (ws + alloc((size_t)N_NODES * DIM));     // raw h1 fp8
    u16*   hb2     = (u16*)  (ws + alloc((size_t)N_NODES * DIM * 2));  // raw h2 bf16
    u16*   Bp1h    = (u16*)  (ws + alloc(256 * 128 * 2));
    u16*   Bp2h    = (u16*)  (ws + alloc(256 * 128 * 2));

    hipMemsetAsync(ws, 0, zero_bytes, stream);

    const int EB = (N_EDGES + 255) / 256;            // 3125
    const int FILLB = EB * NPART;                    // 25000
    const int AGB = N_NODES / 16;                    // 3125 exact
    const int EWB4 = (int)(((long)N_NODES * DIM) / 1024);  // 6250 exact
    const int EWB8 = (int)(((long)N_NODES * DIM) / 2048);  // 3125 exact
    const int PREPB = 32 + EWB4 + FILLB;             // pack + split + partitioned hist

    // prep: pack both B + split x (bf16 + fp8) + XCD-partitioned degree histogram
    k_prep<<<PREPB, 256, 0, stream>>>(W1l, W1r, Bp1h, W2l, W2r, Bp2h, x, xh, xf8,
                                      edst, deg, EWB4);

    // 3-kernel parallel scan -> row_ptr, cursor
    k_scan1<<<SCAN_B, 256, 0, stream>>>(deg, bsum);
    k_scan2<<<1, 256, 0, stream>>>(bsum, bpre);
    k_scan3<<<SCAN_B, 256, 0, stream>>>(deg, bpre, row_ptr, cursor);

    // CSR fill
    k_fill<<<FILLB, 256, 0, stream>>>(esrc, edst, cursor, col_src);

    // stage 1: fused agg+gemm on x (fp8 gather, bf16 root); writes h1 bf16 + fp8
    k_ag<0, 1><<<AGB, 256, 0, stream>>>(xf8, xh, row_ptr, col_src, Bp1h, b1,
                                        stats1, g1, bt1, hb1, h1f8, stats1);

    // stage 2: fused agg+gemm on h1 with BN+relu at operand load (coeffs from stats1)
    k_ag<1, 0><<<AGB, 256, 0, stream>>>(h1f8, hb1, row_ptr, col_src, Bp2h, b2,
                                        stats1, g1, bt1, hb2, h1f8, stats2);

    // epilogue: out = relu(bn(h2) + x), coeffs from stats2
    k_bn_add_relu<<<EWB8, 256, 0, stream>>>(hb2, stats2, g2, bt2, x, out);
}